// Round 1
// baseline (902.345 us; speedup 1.0000x reference)
//
#include <hip/hip_runtime.h>
#include <hip/hip_bf16.h>

#define N_NODES 50000
#define N_EDGES 800000
#define N_GRAPHS 500
#define IN_DIM 128
#define HID 64
#define OUT_DIM 10

// ---------------- degree kernels ----------------
__global__ void deg_init_kernel(float* __restrict__ deg, int n) {
    int i = blockIdx.x * blockDim.x + threadIdx.x;
    if (i < n) deg[i] = 1.0f;  // self-loop
}

__global__ void deg_edge_kernel(const int* __restrict__ dst, float* __restrict__ deg, int e) {
    int i = blockIdx.x * blockDim.x + threadIdx.x;
    if (i < e) atomicAdd(&deg[dst[i]], 1.0f);
}

__global__ void deg_fin_kernel(float* __restrict__ deg, int n) {
    int i = blockIdx.x * blockDim.x + threadIdx.x;
    if (i < n) deg[i] = rsqrtf(deg[i]);  // deg >= 1 always (self-loop)
}

// ---------------- zero ----------------
__global__ void zero_kernel(float* __restrict__ p, int n) {
    int i = blockIdx.x * blockDim.x + threadIdx.x;
    if (i < n) p[i] = 0.0f;
}

// ---------------- linear: out[node,f] = sum_k in[node,k] * W[k,f] ----------------
template <int IN>
__global__ void linear_kernel(const float* __restrict__ in, const float* __restrict__ W,
                              float* __restrict__ out) {
    __shared__ float row[IN];
    int node = blockIdx.x;
    int f = threadIdx.x;  // 64 threads
    for (int k = f; k < IN; k += 64) row[k] = in[node * IN + k];
    __syncthreads();
    float acc = 0.0f;
#pragma unroll
    for (int k = 0; k < IN; ++k) acc += row[k] * W[k * 64 + f];
    out[node * 64 + f] = acc;
}

// ---------------- edge scatter: agg[dst] += hlin[src] * dinv[src]*dinv[dst] ----------------
__global__ void scatter_kernel(const float* __restrict__ hlin, const int* __restrict__ src,
                               const int* __restrict__ dst, const float* __restrict__ dinv,
                               float* __restrict__ agg, int nEdges) {
    int e = blockIdx.x * 4 + (threadIdx.x >> 6);
    if (e >= nEdges) return;
    int f = threadIdx.x & 63;
    int s = src[e];
    int d = dst[e];
    float w = dinv[s] * dinv[d];
    atomicAdd(&agg[d * 64 + f], hlin[s * 64 + f] * w);
}

// ---------------- epilogue: out = relu(agg + hlin*dinv^2 + b) (in-place on agg ok) ----------------
__global__ void finish_kernel(const float* __restrict__ hlin, const float* __restrict__ agg,
                              const float* __restrict__ dinv, const float* __restrict__ b,
                              float* __restrict__ out, int n64) {
    int i = blockIdx.x * blockDim.x + threadIdx.x;
    if (i >= n64) return;
    int node = i >> 6;
    int f = i & 63;
    float di = dinv[node];
    float v = agg[i] + hlin[i] * di * di + b[f];
    out[i] = v > 0.0f ? v : 0.0f;
}

// ---------------- pool scatter ----------------
__global__ void pool_kernel(const float* __restrict__ h, const int* __restrict__ batch,
                            float* __restrict__ pooled, float* __restrict__ counts, int n) {
    int node = blockIdx.x * 4 + (threadIdx.x >> 6);
    if (node >= n) return;
    int f = threadIdx.x & 63;
    int g = batch[node];
    atomicAdd(&pooled[g * 64 + f], h[node * 64 + f]);
    if (f == 0) atomicAdd(&counts[g], 1.0f);
}

// ---------------- MLP head ----------------
__global__ void head_kernel(const float* __restrict__ pooled, const float* __restrict__ counts,
                            const float* __restrict__ W1, const float* __restrict__ b1,
                            const float* __restrict__ W2, const float* __restrict__ b2,
                            float* __restrict__ out, int nGraphs) {
    __shared__ float p[64];
    __shared__ float t[64];
    int g = blockIdx.x;
    int f = threadIdx.x;  // 64 threads
    float inv = 1.0f / fmaxf(counts[g], 1.0f);
    p[f] = pooled[g * 64 + f] * inv;
    __syncthreads();
    float acc = b1[f];
#pragma unroll
    for (int k = 0; k < 64; ++k) acc += p[k] * W1[k * 64 + f];
    t[f] = fmaxf(acc, 0.0f);
    __syncthreads();
    if (f < OUT_DIM) {
        float acc2 = b2[f];
#pragma unroll
        for (int k = 0; k < 64; ++k) acc2 += t[k] * W2[k * OUT_DIM + f];
        out[g * OUT_DIM + f] = acc2;
    }
    if (g == 0 && f == 0) out[nGraphs * OUT_DIM] = 0.0f;  // trailing scalar output
}

extern "C" void kernel_launch(void* const* d_in, const int* in_sizes, int n_in,
                              void* d_out, int out_size, void* d_ws, size_t ws_size,
                              hipStream_t stream) {
    const float* x      = (const float*)d_in[0];
    const int*   eidx   = (const int*)d_in[1];
    const int*   batch  = (const int*)d_in[2];
    const float* W1     = (const float*)d_in[3];
    const float* b1     = (const float*)d_in[4];
    const float* W2     = (const float*)d_in[5];
    const float* b2     = (const float*)d_in[6];
    const float* W3     = (const float*)d_in[7];
    const float* b3     = (const float*)d_in[8];
    const float* lin_W1 = (const float*)d_in[9];
    const float* lin_b1 = (const float*)d_in[10];
    const float* lin_W2 = (const float*)d_in[11];
    const float* lin_b2 = (const float*)d_in[12];
    float* out = (float*)d_out;

    const int E = in_sizes[1] / 2;
    const int N = N_NODES;
    const int NF = N * HID;  // 3.2M

    const int* src = eidx;
    const int* dst = eidx + E;

    // workspace layout (floats)
    float* ws = (float*)d_ws;
    float* buf1   = ws;                 // hlin       [N, 64]
    float* buf2   = buf1 + NF;          // agg / hout [N, 64]
    float* dinv   = buf2 + NF;          // [N]
    float* pooled = dinv + N;           // [500, 64]
    float* counts = pooled + N_GRAPHS * HID;  // [500]

    const int B = 256;

    // degree
    deg_init_kernel<<<(N + B - 1) / B, B, 0, stream>>>(dinv, N);
    deg_edge_kernel<<<(E + B - 1) / B, B, 0, stream>>>(dst, dinv, E);
    deg_fin_kernel<<<(N + B - 1) / B, B, 0, stream>>>(dinv, N);

    // ---- layer 1: x[N,128] -> buf2 ----
    linear_kernel<IN_DIM><<<N, 64, 0, stream>>>(x, W1, buf1);
    zero_kernel<<<(NF + B - 1) / B, B, 0, stream>>>(buf2, NF);
    scatter_kernel<<<(E + 3) / 4, B, 0, stream>>>(buf1, src, dst, dinv, buf2, E);
    finish_kernel<<<(NF + B - 1) / B, B, 0, stream>>>(buf1, buf2, dinv, b1, buf2, NF);

    // ---- layer 2: buf2 -> buf2 ----
    linear_kernel<HID><<<N, 64, 0, stream>>>(buf2, W2, buf1);
    zero_kernel<<<(NF + B - 1) / B, B, 0, stream>>>(buf2, NF);
    scatter_kernel<<<(E + 3) / 4, B, 0, stream>>>(buf1, src, dst, dinv, buf2, E);
    finish_kernel<<<(NF + B - 1) / B, B, 0, stream>>>(buf1, buf2, dinv, b2, buf2, NF);

    // ---- layer 3: buf2 -> buf2 ----
    linear_kernel<HID><<<N, 64, 0, stream>>>(buf2, W3, buf1);
    zero_kernel<<<(NF + B - 1) / B, B, 0, stream>>>(buf2, NF);
    scatter_kernel<<<(E + 3) / 4, B, 0, stream>>>(buf1, src, dst, dinv, buf2, E);
    finish_kernel<<<(NF + B - 1) / B, B, 0, stream>>>(buf1, buf2, dinv, b3, buf2, NF);

    // ---- pool + head ----
    zero_kernel<<<(N_GRAPHS * HID + N_GRAPHS + B - 1) / B, B, 0, stream>>>(pooled, N_GRAPHS * HID + N_GRAPHS);
    pool_kernel<<<(N + 3) / 4, B, 0, stream>>>(buf2, batch, pooled, counts, N);
    head_kernel<<<N_GRAPHS, 64, 0, stream>>>(pooled, counts, lin_W1, lin_b1, lin_W2, lin_b2,
                                             out, N_GRAPHS);
}

// Round 2
// 539.699 us; speedup vs baseline: 1.6719x; 1.6719x over previous
//
#include <hip/hip_runtime.h>
#include <hip/hip_bf16.h>

#define N_NODES 50000
#define N_EDGES 800000
#define N_GRAPHS 500
#define IN_DIM 128
#define HID 64
#define OUT_DIM 10
#define SCAN_CHUNK 1024
#define NB_SCAN ((N_NODES + SCAN_CHUNK - 1) / SCAN_CHUNK)  // 49

// ---------------- zero kernels ----------------
__global__ void zero_f_kernel(float* __restrict__ p, int n) {
    int i = blockIdx.x * blockDim.x + threadIdx.x;
    if (i < n) p[i] = 0.0f;
}
__global__ void zero_i_kernel(int* __restrict__ p, int n) {
    int i = blockIdx.x * blockDim.x + threadIdx.x;
    if (i < n) p[i] = 0;
}

// ---------------- CSR build ----------------
__global__ void hist_kernel(const int* __restrict__ dst, int* __restrict__ cnt, int e) {
    int i = blockIdx.x * blockDim.x + threadIdx.x;
    if (i < e) atomicAdd(&cnt[dst[i]], 1);
}

// per-1024-chunk exclusive scan; also emits dinv = rsqrt(indeg + 1)
__global__ void scan_blocks_kernel(const int* __restrict__ cnt, int* __restrict__ rs,
                                   int* __restrict__ partial, float* __restrict__ dinv, int n) {
    __shared__ int tsum[256];
    int tid = threadIdx.x;
    int base = blockIdx.x * SCAN_CHUNK + tid * 4;
    int v[4];
#pragma unroll
    for (int j = 0; j < 4; ++j) {
        int idx = base + j;
        v[j] = (idx < n) ? cnt[idx] : 0;
        if (idx < n) dinv[idx] = rsqrtf((float)(v[j] + 1));
    }
    int local = v[0] + v[1] + v[2] + v[3];
    tsum[tid] = local;
    __syncthreads();
    // Hillis-Steele inclusive scan over 256 thread sums
    for (int off = 1; off < 256; off <<= 1) {
        int t = (tid >= off) ? tsum[tid - off] : 0;
        __syncthreads();
        tsum[tid] += t;
        __syncthreads();
    }
    int excl = tsum[tid] - local;  // exclusive prefix of this thread's chunk
    int run = excl;
#pragma unroll
    for (int j = 0; j < 4; ++j) {
        int idx = base + j;
        if (idx < n) rs[idx] = run;
        run += v[j];
    }
    if (tid == 255) partial[blockIdx.x] = tsum[255];
}

__global__ void scan_partials_kernel(int* __restrict__ partial, int nb) {
    if (threadIdx.x == 0 && blockIdx.x == 0) {
        int run = 0;
        for (int i = 0; i < nb; ++i) {
            int t = partial[i];
            partial[i] = run;
            run += t;
        }
    }
}

__global__ void scan_add_kernel(int* __restrict__ rs, const int* __restrict__ partial,
                                int* __restrict__ cursor, int n, int e) {
    int i = blockIdx.x * blockDim.x + threadIdx.x;
    if (i < n) {
        int v = rs[i] + partial[i >> 10];
        rs[i] = v;
        cursor[i] = v;
    }
    if (i == 0) rs[n] = e;
}

__global__ void csr_fill_kernel(const int* __restrict__ src, const int* __restrict__ dst,
                                int* __restrict__ cursor, int* __restrict__ csr_src, int e) {
    int i = blockIdx.x * blockDim.x + threadIdx.x;
    if (i < e) {
        int d = dst[i];
        int slot = atomicAdd(&cursor[d], 1);
        csr_src[slot] = src[i];
    }
}

// ---------------- linear: out[node,f] = sum_k in[node,k] * W[k,f] ----------------
template <int IN>
__global__ void linear_kernel(const float* __restrict__ in, const float* __restrict__ W,
                              float* __restrict__ out) {
    __shared__ float row[IN];
    int node = blockIdx.x;
    int f = threadIdx.x;  // 64 threads
    for (int k = f; k < IN; k += 64) row[k] = in[node * IN + k];
    __syncthreads();
    float acc = 0.0f;
#pragma unroll
    for (int k = 0; k < IN; ++k) acc += row[k] * W[k * 64 + f];
    out[node * 64 + f] = acc;
}

// ---------------- CSR gather + self-loop + bias + relu ----------------
__global__ void gather_kernel(const float* __restrict__ hlin, const int* __restrict__ rs,
                              const int* __restrict__ csr_src, const float* __restrict__ dinv,
                              const float* __restrict__ b, float* __restrict__ out, int n) {
    int node = blockIdx.x * 4 + (threadIdx.x >> 6);
    if (node >= n) return;
    int f = threadIdx.x & 63;
    int beg = rs[node], end = rs[node + 1];
    float wd = dinv[node];
    float acc = hlin[node * 64 + f] * wd * wd;  // self-loop term
    int j = beg;
    for (; j + 1 < end; j += 2) {  // 2-way unroll for load ILP
        int s0 = csr_src[j];
        int s1 = csr_src[j + 1];
        float h0 = hlin[s0 * 64 + f];
        float h1 = hlin[s1 * 64 + f];
        acc += h0 * (wd * dinv[s0]);
        acc += h1 * (wd * dinv[s1]);
    }
    if (j < end) {
        int s = csr_src[j];
        acc += hlin[s * 64 + f] * (wd * dinv[s]);
    }
    float v = acc + b[f];
    out[node * 64 + f] = v > 0.0f ? v : 0.0f;
}

// ---------------- pool scatter ----------------
__global__ void pool_kernel(const float* __restrict__ h, const int* __restrict__ batch,
                            float* __restrict__ pooled, float* __restrict__ counts, int n) {
    int node = blockIdx.x * 4 + (threadIdx.x >> 6);
    if (node >= n) return;
    int f = threadIdx.x & 63;
    int g = batch[node];
    atomicAdd(&pooled[g * 64 + f], h[node * 64 + f]);
    if (f == 0) atomicAdd(&counts[g], 1.0f);
}

// ---------------- MLP head ----------------
__global__ void head_kernel(const float* __restrict__ pooled, const float* __restrict__ counts,
                            const float* __restrict__ W1, const float* __restrict__ b1,
                            const float* __restrict__ W2, const float* __restrict__ b2,
                            float* __restrict__ out, int nGraphs) {
    __shared__ float p[64];
    __shared__ float t[64];
    int g = blockIdx.x;
    int f = threadIdx.x;  // 64 threads
    float inv = 1.0f / fmaxf(counts[g], 1.0f);
    p[f] = pooled[g * 64 + f] * inv;
    __syncthreads();
    float acc = b1[f];
#pragma unroll
    for (int k = 0; k < 64; ++k) acc += p[k] * W1[k * 64 + f];
    t[f] = fmaxf(acc, 0.0f);
    __syncthreads();
    if (f < OUT_DIM) {
        float acc2 = b2[f];
#pragma unroll
        for (int k = 0; k < 64; ++k) acc2 += t[k] * W2[k * OUT_DIM + f];
        out[g * OUT_DIM + f] = acc2;
    }
    if (g == 0 && f == 0) out[nGraphs * OUT_DIM] = 0.0f;  // trailing scalar output
}

extern "C" void kernel_launch(void* const* d_in, const int* in_sizes, int n_in,
                              void* d_out, int out_size, void* d_ws, size_t ws_size,
                              hipStream_t stream) {
    const float* x      = (const float*)d_in[0];
    const int*   eidx   = (const int*)d_in[1];
    const int*   batch  = (const int*)d_in[2];
    const float* W1     = (const float*)d_in[3];
    const float* b1     = (const float*)d_in[4];
    const float* W2     = (const float*)d_in[5];
    const float* b2     = (const float*)d_in[6];
    const float* W3     = (const float*)d_in[7];
    const float* b3     = (const float*)d_in[8];
    const float* lin_W1 = (const float*)d_in[9];
    const float* lin_b1 = (const float*)d_in[10];
    const float* lin_W2 = (const float*)d_in[11];
    const float* lin_b2 = (const float*)d_in[12];
    float* out = (float*)d_out;

    const int E = in_sizes[1] / 2;
    const int N = N_NODES;
    const int NF = N * HID;  // 3.2M

    const int* src = eidx;
    const int* dst = eidx + E;

    // workspace layout
    float* ws = (float*)d_ws;
    float* buf1   = ws;                        // hlin       [N, 64]
    float* buf2   = buf1 + NF;                 // h          [N, 64]
    float* dinv   = buf2 + NF;                 // [N]
    float* pooled = dinv + N;                  // [500, 64]
    float* counts = pooled + N_GRAPHS * HID;   // [500]
    int* cnt     = (int*)(counts + N_GRAPHS);  // [N]      in-degree histogram
    int* rs      = cnt + N;                    // [N+1]    CSR row starts
    int* cursor  = rs + N + 1;                 // [N]      fill cursors
    int* csr_src = cursor + N;                 // [E]      src ids grouped by dst
    int* partial = csr_src + E;                // [NB_SCAN]

    const int B = 256;

    // ---- CSR build + dinv ----
    zero_i_kernel<<<(N + B - 1) / B, B, 0, stream>>>(cnt, N);
    hist_kernel<<<(E + B - 1) / B, B, 0, stream>>>(dst, cnt, E);
    scan_blocks_kernel<<<NB_SCAN, 256, 0, stream>>>(cnt, rs, partial, dinv, N);
    scan_partials_kernel<<<1, 64, 0, stream>>>(partial, NB_SCAN);
    scan_add_kernel<<<(N + B - 1) / B, B, 0, stream>>>(rs, partial, cursor, N, E);
    csr_fill_kernel<<<(E + B - 1) / B, B, 0, stream>>>(src, dst, cursor, csr_src, E);

    // ---- layer 1 ----
    linear_kernel<IN_DIM><<<N, 64, 0, stream>>>(x, W1, buf1);
    gather_kernel<<<(N + 3) / 4, B, 0, stream>>>(buf1, rs, csr_src, dinv, b1, buf2, N);

    // ---- layer 2 ----
    linear_kernel<HID><<<N, 64, 0, stream>>>(buf2, W2, buf1);
    gather_kernel<<<(N + 3) / 4, B, 0, stream>>>(buf1, rs, csr_src, dinv, b2, buf2, N);

    // ---- layer 3 ----
    linear_kernel<HID><<<N, 64, 0, stream>>>(buf2, W3, buf1);
    gather_kernel<<<(N + 3) / 4, B, 0, stream>>>(buf1, rs, csr_src, dinv, b3, buf2, N);

    // ---- pool + head ----
    zero_f_kernel<<<(N_GRAPHS * HID + N_GRAPHS + B - 1) / B, B, 0, stream>>>(
        pooled, N_GRAPHS * HID + N_GRAPHS);
    pool_kernel<<<(N + 3) / 4, B, 0, stream>>>(buf2, batch, pooled, counts, N);
    head_kernel<<<N_GRAPHS, 64, 0, stream>>>(pooled, counts, lin_W1, lin_b1, lin_W2, lin_b2,
                                             out, N_GRAPHS);
}

// Round 3
// 432.106 us; speedup vs baseline: 2.0883x; 1.2490x over previous
//
#include <hip/hip_runtime.h>
#include <hip/hip_bf16.h>

#define N_NODES 50000
#define N_EDGES 800000
#define N_GRAPHS 500
#define IN_DIM 128
#define HID 64
#define OUT_DIM 10
#define SCAN_CHUNK 1024
#define NB_SCAN ((N_NODES + SCAN_CHUNK - 1) / SCAN_CHUNK)  // 49

// ---------------- zero ----------------
__global__ void zero_i_kernel(int* __restrict__ p, int n) {
    int i = blockIdx.x * blockDim.x + threadIdx.x;
    if (i < n) p[i] = 0;
}

// ---------------- CSR build ----------------
__global__ void hist_kernel(const int* __restrict__ dst, int* __restrict__ cnt, int e) {
    int i = blockIdx.x * blockDim.x + threadIdx.x;
    if (i < e) atomicAdd(&cnt[dst[i]], 1);
}

// per-1024-chunk exclusive scan; also emits dinv = rsqrt(indeg + 1)
__global__ void scan_blocks_kernel(const int* __restrict__ cnt, int* __restrict__ rs,
                                   int* __restrict__ partial, float* __restrict__ dinv, int n) {
    __shared__ int tsum[256];
    int tid = threadIdx.x;
    int base = blockIdx.x * SCAN_CHUNK + tid * 4;
    int v[4];
#pragma unroll
    for (int j = 0; j < 4; ++j) {
        int idx = base + j;
        v[j] = (idx < n) ? cnt[idx] : 0;
        if (idx < n) dinv[idx] = rsqrtf((float)(v[j] + 1));
    }
    int local = v[0] + v[1] + v[2] + v[3];
    tsum[tid] = local;
    __syncthreads();
    for (int off = 1; off < 256; off <<= 1) {
        int t = (tid >= off) ? tsum[tid - off] : 0;
        __syncthreads();
        tsum[tid] += t;
        __syncthreads();
    }
    int excl = tsum[tid] - local;
    int run = excl;
#pragma unroll
    for (int j = 0; j < 4; ++j) {
        int idx = base + j;
        if (idx < n) rs[idx] = run;
        run += v[j];
    }
    if (tid == 255) partial[blockIdx.x] = tsum[255];
}

__global__ void scan_partials_kernel(int* __restrict__ partial, int nb) {
    if (threadIdx.x == 0 && blockIdx.x == 0) {
        int run = 0;
        for (int i = 0; i < nb; ++i) {
            int t = partial[i];
            partial[i] = run;
            run += t;
        }
    }
}

__global__ void scan_add_kernel(int* __restrict__ rs, const int* __restrict__ partial,
                                int* __restrict__ cursor, int n, int e) {
    int i = blockIdx.x * blockDim.x + threadIdx.x;
    if (i < n) {
        int v = rs[i] + partial[i >> 10];
        rs[i] = v;
        cursor[i] = v;
    }
    if (i == 0) rs[n] = e;
}

__global__ void csr_fill_kernel(const int* __restrict__ src, const int* __restrict__ dst,
                                int* __restrict__ cursor, int* __restrict__ csr_src, int e) {
    int i = blockIdx.x * blockDim.x + threadIdx.x;
    if (i < e) {
        int d = dst[i];
        int slot = atomicAdd(&cursor[d], 1);
        csr_src[slot] = src[i];
    }
}

// ---------------- linear (+ dinv pre-scale): out[node,f] = dinv[node] * sum_k in[node,k]*W[k,f]
template <int IN>
__global__ void linear_kernel(const float* __restrict__ in, const float* __restrict__ W,
                              const float* __restrict__ dinv, float* __restrict__ out) {
    __shared__ float row[IN];
    int node = blockIdx.x;
    int f = threadIdx.x;  // 64 threads
    for (int k = f; k < IN; k += 64) row[k] = in[node * IN + k];
    __syncthreads();
    float acc = 0.0f;
#pragma unroll
    for (int k = 0; k < IN; ++k) acc += row[k] * W[k * 64 + f];
    out[node * 64 + f] = acc * dinv[node];
}

// ---------------- CSR gather on pre-scaled hs; fused self-loop+bias+relu ----------------
// out[d,f] = relu( dinv[d] * ( hs[d,f] + sum_{s in N(d)} hs[s,f] ) + b[f] )
__global__ void gather_kernel(const float* __restrict__ hs, const int* __restrict__ rs,
                              const int* __restrict__ csr_src, const float* __restrict__ dinv,
                              const float* __restrict__ b, float* __restrict__ out, int n) {
    int wave = __builtin_amdgcn_readfirstlane(threadIdx.x >> 6);  // wave-uniform
    int node = blockIdx.x * 4 + wave;
    if (node >= n) return;
    int f = threadIdx.x & 63;
    int beg = rs[node], end = rs[node + 1];
    float acc = hs[node * 64 + f];  // self-loop term (pre-scaled)
    int j = beg;
    for (; j + 3 < end; j += 4) {
        int s0 = csr_src[j];
        int s1 = csr_src[j + 1];
        int s2 = csr_src[j + 2];
        int s3 = csr_src[j + 3];
        float h0 = hs[s0 * 64 + f];
        float h1 = hs[s1 * 64 + f];
        float h2 = hs[s2 * 64 + f];
        float h3 = hs[s3 * 64 + f];
        acc += h0 + h1 + h2 + h3;
    }
    for (; j < end; ++j) acc += hs[csr_src[j] * 64 + f];
    float v = acc * dinv[node] + b[f];
    out[node * 64 + f] = v > 0.0f ? v : 0.0f;
}

// ---------------- fused segmented mean-pool + MLP head ----------------
__device__ __forceinline__ int lower_bound_dev(const int* __restrict__ a, int n, int v) {
    int lo = 0, hi = n;
    while (lo < hi) {
        int m = (lo + hi) >> 1;
        if (a[m] < v) lo = m + 1; else hi = m;
    }
    return lo;
}

__global__ void pool_head_kernel(const float* __restrict__ h, const int* __restrict__ batch,
                                 const float* __restrict__ W1, const float* __restrict__ b1,
                                 const float* __restrict__ W2, const float* __restrict__ b2,
                                 float* __restrict__ out, int nNodes, int nGraphs) {
    __shared__ float p[64];
    __shared__ float t[64];
    int g = blockIdx.x;
    int f = threadIdx.x;  // 64 threads
    // batch is sorted: node range of graph g via binary search (uniform across lanes)
    int lo = lower_bound_dev(batch, nNodes, g);
    int hi = lower_bound_dev(batch, nNodes, g + 1);
    float sum = 0.0f;
    for (int i = lo; i < hi; ++i) sum += h[i * 64 + f];
    float inv = 1.0f / fmaxf((float)(hi - lo), 1.0f);
    p[f] = sum * inv;
    __syncthreads();
    float acc = b1[f];
#pragma unroll
    for (int k = 0; k < 64; ++k) acc += p[k] * W1[k * 64 + f];
    t[f] = fmaxf(acc, 0.0f);
    __syncthreads();
    if (f < OUT_DIM) {
        float acc2 = b2[f];
#pragma unroll
        for (int k = 0; k < 64; ++k) acc2 += t[k] * W2[k * OUT_DIM + f];
        out[g * OUT_DIM + f] = acc2;
    }
    if (g == 0 && f == 0) out[nGraphs * OUT_DIM] = 0.0f;  // trailing scalar output
}

extern "C" void kernel_launch(void* const* d_in, const int* in_sizes, int n_in,
                              void* d_out, int out_size, void* d_ws, size_t ws_size,
                              hipStream_t stream) {
    const float* x      = (const float*)d_in[0];
    const int*   eidx   = (const int*)d_in[1];
    const int*   batch  = (const int*)d_in[2];
    const float* W1     = (const float*)d_in[3];
    const float* b1     = (const float*)d_in[4];
    const float* W2     = (const float*)d_in[5];
    const float* b2     = (const float*)d_in[6];
    const float* W3     = (const float*)d_in[7];
    const float* b3     = (const float*)d_in[8];
    const float* lin_W1 = (const float*)d_in[9];
    const float* lin_b1 = (const float*)d_in[10];
    const float* lin_W2 = (const float*)d_in[11];
    const float* lin_b2 = (const float*)d_in[12];
    float* out = (float*)d_out;

    const int E = in_sizes[1] / 2;
    const int N = N_NODES;
    const int NF = N * HID;

    const int* src = eidx;
    const int* dst = eidx + E;

    // workspace layout
    float* ws = (float*)d_ws;
    float* buf1 = ws;                  // hs (pre-scaled linear out) [N, 64]
    float* buf2 = buf1 + NF;           // h                          [N, 64]
    float* dinv = buf2 + NF;           // [N]
    int* cnt     = (int*)(dinv + N);   // [N]
    int* rs      = cnt + N;            // [N+1]
    int* cursor  = rs + N + 1;         // [N]
    int* csr_src = cursor + N;         // [E]
    int* partial = csr_src + E;        // [NB_SCAN]

    const int B = 256;

    // ---- CSR build + dinv ----
    zero_i_kernel<<<(N + B - 1) / B, B, 0, stream>>>(cnt, N);
    hist_kernel<<<(E + B - 1) / B, B, 0, stream>>>(dst, cnt, E);
    scan_blocks_kernel<<<NB_SCAN, 256, 0, stream>>>(cnt, rs, partial, dinv, N);
    scan_partials_kernel<<<1, 64, 0, stream>>>(partial, NB_SCAN);
    scan_add_kernel<<<(N + B - 1) / B, B, 0, stream>>>(rs, partial, cursor, N, E);
    csr_fill_kernel<<<(E + B - 1) / B, B, 0, stream>>>(src, dst, cursor, csr_src, E);

    // ---- layer 1 ----
    linear_kernel<IN_DIM><<<N, 64, 0, stream>>>(x, W1, dinv, buf1);
    gather_kernel<<<(N + 3) / 4, B, 0, stream>>>(buf1, rs, csr_src, dinv, b1, buf2, N);

    // ---- layer 2 ----
    linear_kernel<HID><<<N, 64, 0, stream>>>(buf2, W2, dinv, buf1);
    gather_kernel<<<(N + 3) / 4, B, 0, stream>>>(buf1, rs, csr_src, dinv, b2, buf2, N);

    // ---- layer 3 ----
    linear_kernel<HID><<<N, 64, 0, stream>>>(buf2, W3, dinv, buf1);
    gather_kernel<<<(N + 3) / 4, B, 0, stream>>>(buf1, rs, csr_src, dinv, b3, buf2, N);

    // ---- fused pool + head ----
    pool_head_kernel<<<N_GRAPHS, 64, 0, stream>>>(buf2, batch, lin_W1, lin_b1, lin_W2, lin_b2,
                                                  out, N, N_GRAPHS);
}

// Round 4
// 404.772 us; speedup vs baseline: 2.2293x; 1.0675x over previous
//
#include <hip/hip_runtime.h>
#include <hip/hip_bf16.h>

#define N_NODES 50000
#define N_EDGES 800000
#define N_GRAPHS 500
#define IN_DIM 128
#define HID 64
#define OUT_DIM 10
#define SCAN_CHUNK 1024
#define NB_SCAN ((N_NODES + SCAN_CHUNK - 1) / SCAN_CHUNK)  // 49

// ---------------- zero ----------------
__global__ void zero_i_kernel(int* __restrict__ p, int n) {
    int i = blockIdx.x * blockDim.x + threadIdx.x;
    if (i < n) p[i] = 0;
}

// ---------------- CSR build ----------------
__global__ void hist_kernel(const int* __restrict__ dst, int* __restrict__ cnt, int e) {
    int i = blockIdx.x * blockDim.x + threadIdx.x;
    if (i < e) atomicAdd(&cnt[dst[i]], 1);
}

// per-1024-chunk exclusive scan; also emits dinv = rsqrt(indeg + 1)
__global__ void scan_blocks_kernel(const int* __restrict__ cnt, int* __restrict__ rs,
                                   int* __restrict__ partial, float* __restrict__ dinv, int n) {
    __shared__ int tsum[256];
    int tid = threadIdx.x;
    int base = blockIdx.x * SCAN_CHUNK + tid * 4;
    int v[4];
#pragma unroll
    for (int j = 0; j < 4; ++j) {
        int idx = base + j;
        v[j] = (idx < n) ? cnt[idx] : 0;
        if (idx < n) dinv[idx] = rsqrtf((float)(v[j] + 1));
    }
    int local = v[0] + v[1] + v[2] + v[3];
    tsum[tid] = local;
    __syncthreads();
    for (int off = 1; off < 256; off <<= 1) {
        int t = (tid >= off) ? tsum[tid - off] : 0;
        __syncthreads();
        tsum[tid] += t;
        __syncthreads();
    }
    int excl = tsum[tid] - local;
    int run = excl;
#pragma unroll
    for (int j = 0; j < 4; ++j) {
        int idx = base + j;
        if (idx < n) rs[idx] = run;
        run += v[j];
    }
    if (tid == 255) partial[blockIdx.x] = tsum[255];
}

__global__ void scan_partials_kernel(int* __restrict__ partial, int nb) {
    if (threadIdx.x == 0 && blockIdx.x == 0) {
        int run = 0;
        for (int i = 0; i < nb; ++i) {
            int t = partial[i];
            partial[i] = run;
            run += t;
        }
    }
}

__global__ void scan_add_kernel(int* __restrict__ rs, const int* __restrict__ partial,
                                int* __restrict__ cursor, int n, int e) {
    int i = blockIdx.x * blockDim.x + threadIdx.x;
    if (i < n) {
        int v = rs[i] + partial[i >> 10];
        rs[i] = v;
        cursor[i] = v;
    }
    if (i == 0) rs[n] = e;
}

__global__ void csr_fill_kernel(const int* __restrict__ src, const int* __restrict__ dst,
                                int* __restrict__ cursor, int* __restrict__ csr_src, int e) {
    int i = blockIdx.x * blockDim.x + threadIdx.x;
    if (i < e) {
        int d = dst[i];
        int slot = atomicAdd(&cursor[d], 1);
        csr_src[slot] = src[i];
    }
}

// ---------------- tiled linear (+ dinv pre-scale) ----------------
// C[node,f] = dinv[node] * sum_k A[node,k] * W[k,f]
// 256 threads, 64-node x 64-feat tile, 4x4 micro-tile per thread.
template <int K>
__global__ __launch_bounds__(256) void linear_tiled_kernel(
    const float* __restrict__ A, const float* __restrict__ W,
    const float* __restrict__ dinv, float* __restrict__ C, int n) {
    __shared__ float As[64][K + 4];  // +4 pad: keeps float4 alignment, breaks pow2 bank stride
    __shared__ float Ws[K][64];
    int tid = threadIdx.x;
    int tx = tid & 15;   // feat group
    int ty = tid >> 4;   // node group
    int block0 = blockIdx.x * 64;
    int rows = n - block0;
    if (rows > 64) rows = 64;

    // stage A tile: consecutive nodes => one contiguous chunk of rows*K floats
    const float* Abase = A + (size_t)block0 * K;
    int totalA4 = (rows * K) >> 2;
    for (int i4 = tid; i4 < totalA4; i4 += 256) {
        int i = i4 << 2;
        float4 v = *(const float4*)(Abase + i);
        *(float4*)&As[i / K][i % K] = v;
    }
    // stage W (contiguous K*64 floats)
    {
        const float4* Wv = (const float4*)W;
        float4* Wsv = (float4*)&Ws[0][0];
        for (int i = tid; i < K * 16; i += 256) Wsv[i] = Wv[i];
    }
    __syncthreads();

    float acc[4][4] = {};
    for (int k = 0; k < K; k += 4) {
        float4 a[4];
#pragma unroll
        for (int i = 0; i < 4; ++i) a[i] = *(const float4*)&As[ty * 4 + i][k];
        float4 w[4];
#pragma unroll
        for (int kk = 0; kk < 4; ++kk) w[kk] = *(const float4*)&Ws[k + kk][tx * 4];
#pragma unroll
        for (int i = 0; i < 4; ++i) {
            float av[4] = {a[i].x, a[i].y, a[i].z, a[i].w};
#pragma unroll
            for (int kk = 0; kk < 4; ++kk) {
                acc[i][0] += av[kk] * w[kk].x;
                acc[i][1] += av[kk] * w[kk].y;
                acc[i][2] += av[kk] * w[kk].z;
                acc[i][3] += av[kk] * w[kk].w;
            }
        }
    }

#pragma unroll
    for (int i = 0; i < 4; ++i) {
        int r = ty * 4 + i;
        if (r < rows) {
            float s = dinv[block0 + r];
            float4 v = {acc[i][0] * s, acc[i][1] * s, acc[i][2] * s, acc[i][3] * s};
            *(float4*)&C[(size_t)(block0 + r) * 64 + tx * 4] = v;
        }
    }
}

// ---------------- CSR gather on pre-scaled hs; fused self-loop+bias+relu ----------------
// out[d,f] = relu( dinv[d] * ( hs[d,f] + sum_{s in N(d)} hs[s,f] ) + b[f] )
__global__ void gather_kernel(const float* __restrict__ hs, const int* __restrict__ rs,
                              const int* __restrict__ csr_src, const float* __restrict__ dinv,
                              const float* __restrict__ b, float* __restrict__ out, int n) {
    int wave = __builtin_amdgcn_readfirstlane(threadIdx.x >> 6);  // wave-uniform
    int node = blockIdx.x * 4 + wave;
    if (node >= n) return;
    int f = threadIdx.x & 63;
    int beg = rs[node], end = rs[node + 1];
    float acc = hs[node * 64 + f];  // self-loop term (pre-scaled)
    int j = beg;
    for (; j + 3 < end; j += 4) {
        int s0 = csr_src[j];
        int s1 = csr_src[j + 1];
        int s2 = csr_src[j + 2];
        int s3 = csr_src[j + 3];
        float h0 = hs[s0 * 64 + f];
        float h1 = hs[s1 * 64 + f];
        float h2 = hs[s2 * 64 + f];
        float h3 = hs[s3 * 64 + f];
        acc += h0 + h1 + h2 + h3;
    }
    for (; j < end; ++j) acc += hs[csr_src[j] * 64 + f];
    float v = acc * dinv[node] + b[f];
    out[node * 64 + f] = v > 0.0f ? v : 0.0f;
}

// ---------------- fused segmented mean-pool + MLP head ----------------
__device__ __forceinline__ int lower_bound_dev(const int* __restrict__ a, int n, int v) {
    int lo = 0, hi = n;
    while (lo < hi) {
        int m = (lo + hi) >> 1;
        if (a[m] < v) lo = m + 1; else hi = m;
    }
    return lo;
}

__global__ void pool_head_kernel(const float* __restrict__ h, const int* __restrict__ batch,
                                 const float* __restrict__ W1, const float* __restrict__ b1,
                                 const float* __restrict__ W2, const float* __restrict__ b2,
                                 float* __restrict__ out, int nNodes, int nGraphs) {
    __shared__ float p[64];
    __shared__ float t[64];
    int g = blockIdx.x;
    int f = threadIdx.x;  // 64 threads
    int lo = lower_bound_dev(batch, nNodes, g);
    int hi = lower_bound_dev(batch, nNodes, g + 1);
    float sum = 0.0f;
    for (int i = lo; i < hi; ++i) sum += h[i * 64 + f];
    float inv = 1.0f / fmaxf((float)(hi - lo), 1.0f);
    p[f] = sum * inv;
    __syncthreads();
    float acc = b1[f];
#pragma unroll
    for (int k = 0; k < 64; ++k) acc += p[k] * W1[k * 64 + f];
    t[f] = fmaxf(acc, 0.0f);
    __syncthreads();
    if (f < OUT_DIM) {
        float acc2 = b2[f];
#pragma unroll
        for (int k = 0; k < 64; ++k) acc2 += t[k] * W2[k * OUT_DIM + f];
        out[g * OUT_DIM + f] = acc2;
    }
    if (g == 0 && f == 0) out[nGraphs * OUT_DIM] = 0.0f;  // trailing scalar output
}

extern "C" void kernel_launch(void* const* d_in, const int* in_sizes, int n_in,
                              void* d_out, int out_size, void* d_ws, size_t ws_size,
                              hipStream_t stream) {
    const float* x      = (const float*)d_in[0];
    const int*   eidx   = (const int*)d_in[1];
    const int*   batch  = (const int*)d_in[2];
    const float* W1     = (const float*)d_in[3];
    const float* b1     = (const float*)d_in[4];
    const float* W2     = (const float*)d_in[5];
    const float* b2     = (const float*)d_in[6];
    const float* W3     = (const float*)d_in[7];
    const float* b3     = (const float*)d_in[8];
    const float* lin_W1 = (const float*)d_in[9];
    const float* lin_b1 = (const float*)d_in[10];
    const float* lin_W2 = (const float*)d_in[11];
    const float* lin_b2 = (const float*)d_in[12];
    float* out = (float*)d_out;

    const int E = in_sizes[1] / 2;
    const int N = N_NODES;
    const int NF = N * HID;

    const int* src = eidx;
    const int* dst = eidx + E;

    // workspace layout
    float* ws = (float*)d_ws;
    float* buf1 = ws;                  // hs (pre-scaled linear out) [N, 64]
    float* buf2 = buf1 + NF;           // h                          [N, 64]
    float* dinv = buf2 + NF;           // [N]
    int* cnt     = (int*)(dinv + N);   // [N]
    int* rs      = cnt + N;            // [N+1]
    int* cursor  = rs + N + 1;         // [N]
    int* csr_src = cursor + N;         // [E]
    int* partial = csr_src + E;        // [NB_SCAN]

    const int B = 256;
    const int GEMM_BLOCKS = (N + 63) / 64;

    // ---- CSR build + dinv ----
    zero_i_kernel<<<(N + B - 1) / B, B, 0, stream>>>(cnt, N);
    hist_kernel<<<(E + B - 1) / B, B, 0, stream>>>(dst, cnt, E);
    scan_blocks_kernel<<<NB_SCAN, 256, 0, stream>>>(cnt, rs, partial, dinv, N);
    scan_partials_kernel<<<1, 64, 0, stream>>>(partial, NB_SCAN);
    scan_add_kernel<<<(N + B - 1) / B, B, 0, stream>>>(rs, partial, cursor, N, E);
    csr_fill_kernel<<<(E + B - 1) / B, B, 0, stream>>>(src, dst, cursor, csr_src, E);

    // ---- layer 1 ----
    linear_tiled_kernel<IN_DIM><<<GEMM_BLOCKS, 256, 0, stream>>>(x, W1, dinv, buf1, N);
    gather_kernel<<<(N + 3) / 4, B, 0, stream>>>(buf1, rs, csr_src, dinv, b1, buf2, N);

    // ---- layer 2 ----
    linear_tiled_kernel<HID><<<GEMM_BLOCKS, 256, 0, stream>>>(buf2, W2, dinv, buf1, N);
    gather_kernel<<<(N + 3) / 4, B, 0, stream>>>(buf1, rs, csr_src, dinv, b2, buf2, N);

    // ---- layer 3 ----
    linear_tiled_kernel<HID><<<GEMM_BLOCKS, 256, 0, stream>>>(buf2, W3, dinv, buf1, N);
    gather_kernel<<<(N + 3) / 4, B, 0, stream>>>(buf1, rs, csr_src, dinv, b3, buf2, N);

    // ---- fused pool + head ----
    pool_head_kernel<<<N_GRAPHS, 64, 0, stream>>>(buf2, batch, lin_W1, lin_b1, lin_W2, lin_b2,
                                                  out, N, N_GRAPHS);
}